// Round 18
// baseline (339.340 us; speedup 1.0000x reference)
//
#include <hip/hip_runtime.h>
#include <math.h>

// GaussianAvatar R18 = R16 (267.8us best) + ONE change: NON-TEMPORAL stores
// in finalize_all (NPT=4). R17's counters finally exposed finalize: FETCH
// 255MB/dispatch = ~0% L2 hit on rec gathers — the 358MB of streaming output
// writes allocate in L2 and evict the 3.2MB/XCD rec working set. nt-stores
// bypass L2 on the write path so rec stays resident. (R9's nt test was
// bundled with cos-BG2 which R14 showed is the regressor; this isolates nt.)
namespace {
constexpr int kB = 32;
constexpr int kV = 25000;
constexpr int kJ = 20;
constexpr int kF = 50000;
constexpr int kN = 200000;
constexpr int kCap = 40;

constexpr float kEps = 1e-8f;

constexpr size_t OFF_MEANS  = 0;
constexpr size_t OFF_COLORS = (size_t)kB * kN * 3;
constexpr size_t OFF_OPAC   = OFF_COLORS + (size_t)kB * kN * 3;
constexpr size_t OFF_SCALE  = OFF_OPAC + (size_t)kB * kN;
constexpr size_t OFF_ROT    = OFF_SCALE + (size_t)kB * kN * 3;

// workspace layout (bytes)
constexpr size_t WS_A    = 0;
constexpr size_t WS_CNT  = 32768;
constexpr size_t WS_TRI  = 262144;               // kCap*kV uint = 4MB
constexpr size_t WS_REC  = 4325376;              // B*V*2 float4 = 25.6MB
constexpr size_t WS_VW   = WS_REC + 25600000;    // B*V float4 = 12.8MB
constexpr size_t WS_END  = WS_VW + 12800000;     // ~42.7MB
}

__device__ __forceinline__ float sigm(float x) {
    return 1.0f / (1.0f + __expf(-x));
}
__device__ __forceinline__ float eclip(float x) {
    return fminf(fmaxf(__expf(x), 0.0005f), 0.05f);
}

// native clang vector for nontemporal builtins (same 16B layout as float4)
typedef float f4 __attribute__((ext_vector_type(4)));
__device__ __forceinline__ void nt_store4(float* p, float a, float b,
                                          float c, float d) {
    f4 v = {a, b, c, d};
    __builtin_nontemporal_store(v, (f4*)p);
}
__device__ __forceinline__ void nt_store4v(float* p, float4 v) {
    nt_store4(p, v.x, v.y, v.z, v.w);
}

// ---------------------------------------------------------------------------
__global__ void zero_cnt_kernel(int* __restrict__ cnt) {
    int i = blockIdx.x * blockDim.x + threadIdx.x;
    if (i < kV) cnt[i] = 0;
}

// ---------------------------------------------------------------------------
// Bucket fill: tri[slot][v] = ia | ib<<15 | swap<<30 (v is base corner;
// swap=k==1 preserves orientation).
// ---------------------------------------------------------------------------
__global__ void fill_bucket_kernel(const int* __restrict__ faces,
                                   int* __restrict__ cursor,
                                   unsigned int* __restrict__ tri) {
    int f = blockIdx.x * blockDim.x + threadIdx.x;
    if (f >= kF) return;
    int i0 = faces[f * 3 + 0];
    int i1 = faces[f * 3 + 1];
    int i2 = faces[f * 3 + 2];
    const int vs[3] = {i0, i1, i2};
#pragma unroll
    for (int k = 0; k < 3; ++k) {
        int v = vs[k];
        unsigned int ia = (k == 0) ? (unsigned)i1 : (unsigned)i0;
        unsigned int ib = (k == 2) ? (unsigned)i1 : (unsigned)i2;
        unsigned int swap = (k == 1) ? 1u : 0u;
        unsigned int rec = ia | (ib << 15) | (swap << 30);
        int p = atomicAdd(&cursor[v], 1);
        if (p < kCap) tri[(size_t)p * kV + v] = rec;  // slot-major
    }
}

// ---------------------------------------------------------------------------
__global__ void jt_kernel(const float* __restrict__ pose,
                          const float* __restrict__ jr,
                          float* __restrict__ A) {
    int b = threadIdx.x;
    if (b >= kB) return;

    float Gr[9], Gt[3];
    for (int j = 0; j < kJ; ++j) {
        float ax = pose[b * (kJ * 3) + j * 3 + 0];
        float ay = pose[b * (kJ * 3) + j * 3 + 1];
        float az = pose[b * (kJ * 3) + j * 3 + 2];
        float t2 = ax * ax + ay * ay + az * az + 1e-12f;
        float th = sqrtf(t2);
        float inv = 1.0f / th;
        float ux = ax * inv, uy = ay * inv, uz = az * inv;
        float s = sinf(th), c = cosf(th), oc = 1.0f - c;
        float R[9];
        R[0] = 1.0f + oc * (-(uy * uy + uz * uz));
        R[1] = -s * uz + oc * (ux * uy);
        R[2] =  s * uy + oc * (ux * uz);
        R[3] =  s * uz + oc * (ux * uy);
        R[4] = 1.0f + oc * (-(ux * ux + uz * uz));
        R[5] = -s * ux + oc * (uy * uz);
        R[6] = -s * uy + oc * (ux * uz);
        R[7] =  s * ux + oc * (uy * uz);
        R[8] = 1.0f + oc * (-(ux * ux + uy * uy));

        float jx = jr[j * 3 + 0], jy = jr[j * 3 + 1], jz = jr[j * 3 + 2];

        if (j == 0) {
            for (int k = 0; k < 9; ++k) Gr[k] = R[k];
            Gt[0] = jx; Gt[1] = jy; Gt[2] = jz;
        } else {
            float pjx = jr[(j - 1) * 3 + 0];
            float pjy = jr[(j - 1) * 3 + 1];
            float pjz = jr[(j - 1) * 3 + 2];
            float ltx = jx - pjx, lty = jy - pjy, ltz = jz - pjz;
            float nR[9], nT[3];
            for (int r = 0; r < 3; ++r) {
                float g0 = Gr[r * 3 + 0], g1 = Gr[r * 3 + 1], g2 = Gr[r * 3 + 2];
                nR[r * 3 + 0] = g0 * R[0] + g1 * R[3] + g2 * R[6];
                nR[r * 3 + 1] = g0 * R[1] + g1 * R[4] + g2 * R[7];
                nR[r * 3 + 2] = g0 * R[2] + g1 * R[5] + g2 * R[8];
                nT[r] = g0 * ltx + g1 * lty + g2 * ltz + Gt[r];
            }
            for (int k = 0; k < 9; ++k) Gr[k] = nR[k];
            Gt[0] = nT[0]; Gt[1] = nT[1]; Gt[2] = nT[2];
        }

        float tgx = Gt[0] - (Gr[0] * jx + Gr[1] * jy + Gr[2] * jz);
        float tgy = Gt[1] - (Gr[3] * jx + Gr[4] * jy + Gr[5] * jz);
        float tgz = Gt[2] - (Gr[6] * jx + Gr[7] * jy + Gr[8] * jz);
        float* Ao = A + ((size_t)b * kJ + j) * 12;
        Ao[0] = Gr[0]; Ao[1] = Gr[1]; Ao[2]  = Gr[2]; Ao[3]  = tgx;
        Ao[4] = Gr[3]; Ao[5] = Gr[4]; Ao[6]  = Gr[5]; Ao[7]  = tgy;
        Ao[8] = Gr[6]; Ao[9] = Gr[7]; Ao[10] = Gr[8]; Ao[11] = tgz;
    }
}

// ---------------------------------------------------------------------------
// Kernel 2: LBS skinning. b = blockIdx.x (XCD = b%8).
// ---------------------------------------------------------------------------
__global__ void skin_kernel(const float* __restrict__ A,
                            const float* __restrict__ sw,
                            const float* __restrict__ vt,
                            const float* __restrict__ scale,
                            const float* __restrict__ trans,
                            float4* __restrict__ Vw) {
    int b = blockIdx.x;
    int v = blockIdx.y * blockDim.x + threadIdx.x;
    __shared__ float sA[kJ * 12];
    if (threadIdx.x < kJ * 12) sA[threadIdx.x] = A[(size_t)b * kJ * 12 + threadIdx.x];
    __syncthreads();
    if (v >= kV) return;

    const float4* sw4 = (const float4*)(sw + (size_t)v * kJ);
    float w[kJ];
#pragma unroll
    for (int q = 0; q < 5; ++q) {
        float4 f = sw4[q];
        w[q * 4 + 0] = f.x; w[q * 4 + 1] = f.y;
        w[q * 4 + 2] = f.z; w[q * 4 + 3] = f.w;
    }

    float T[12];
#pragma unroll
    for (int k = 0; k < 12; ++k) T[k] = 0.0f;
#pragma unroll
    for (int j = 0; j < kJ; ++j) {
        float wj = w[j];
#pragma unroll
        for (int k = 0; k < 12; ++k) T[k] += wj * sA[j * 12 + k];
    }
    float x = vt[v * 3 + 0], y = vt[v * 3 + 1], z = vt[v * 3 + 2];
    float px = T[0] * x + T[1] * y + T[2]  * z + T[3];
    float py = T[4] * x + T[5] * y + T[6]  * z + T[7];
    float pz = T[8] * x + T[9] * y + T[10] * z + T[11];
    float s = scale[b];
    float tx = trans[b * 3 + 0], ty = trans[b * 3 + 1], tz = trans[b * 3 + 2];
    Vw[(size_t)b * kV + v] = make_float4(px * s + tx, py * s + ty, pz * s + tz, 0.0f);
}

// ---------------------------------------------------------------------------
// Kernel 3: frame + quat; v is always the base corner (2 gathers/face).
// ---------------------------------------------------------------------------
__global__ void frame_kernel(const float4* __restrict__ Vw,
                             const int* __restrict__ cnt,
                             const unsigned int* __restrict__ tri,
                             float4* __restrict__ rec) {
    int b = blockIdx.x;
    int v = blockIdx.y * blockDim.x + threadIdx.x;
    if (v >= kV) return;
    const float4* base = Vw + (size_t)b * kV;
    float4 me = base[v];

    int deg = min(cnt[v], kCap);
    float sx = 0.0f, sy = 0.0f, sz = 0.0f;
    for (int i = 0; i < deg; ++i) {
        unsigned int r = tri[(size_t)i * kV + v];
        int ia = (int)(r & 0x7fffu);
        int ib = (int)((r >> 15) & 0x7fffu);
        bool swap = (r >> 30) != 0u;
        int j1 = swap ? ib : ia;
        int j2 = swap ? ia : ib;
        float4 c1 = base[j1];
        float4 c2 = base[j2];
        float e1x = c1.x - me.x, e1y = c1.y - me.y, e1z = c1.z - me.z;
        float e2x = c2.x - me.x, e2y = c2.y - me.y, e2z = c2.z - me.z;
        sx += e1y * e2z - e1z * e2y;
        sy += e1z * e2x - e1x * e2z;
        sz += e1x * e2y - e1y * e2x;
    }

    float ninv = rsqrtf(sx * sx + sy * sy + sz * sz + 1e-12f);
    float nx = sx * ninv, ny = sy * ninv, nz = sz * ninv;

    bool small = fabsf(nx) < 0.9f;
    float refx = small ? 1.0f : 0.0f;
    float refz = small ? 0.0f : 1.0f;
    float d = refx * nx + refz * nz;
    float tx0 = refx - d * nx, ty0 = -d * ny, tz0 = refz - d * nz;
    float tinv = rsqrtf(tx0 * tx0 + ty0 * ty0 + tz0 * tz0 + 1e-12f);
    float tx = tx0 * tinv, ty = ty0 * tinv, tz = tz0 * tinv;

    float btx = ny * tz - nz * ty;
    float bty = nz * tx - nx * tz;
    float btz = nx * ty - ny * tx;

    float r00 = tx, r01 = btx, r02 = nx;
    float r10 = ty, r11 = bty, r12 = ny;
    float r20 = tz, r21 = btz, r22 = nz;
    float tr = r00 + r11 + r22;
    float q0, q1, q2, q3;
    if (tr > 0.0f) {
        float s = sqrtf(fmaxf(tr + 1.0f, kEps)) * 2.0f;
        q0 = 0.25f * s;
        q1 = (r21 - r12) / s;
        q2 = (r02 - r20) / s;
        q3 = (r10 - r01) / s;
    } else if (r00 > r11 && r00 > r22) {
        float s = sqrtf(fmaxf(1.0f + r00 - r11 - r22, kEps)) * 2.0f;
        q0 = (r21 - r12) / s;
        q1 = 0.25f * s;
        q2 = (r01 + r10) / s;
        q3 = (r02 + r20) / s;
    } else if (r11 > r22) {
        float s = sqrtf(fmaxf(1.0f + r11 - r00 - r22, kEps)) * 2.0f;
        q0 = (r02 - r20) / s;
        q1 = (r01 + r10) / s;
        q2 = 0.25f * s;
        q3 = (r12 + r21) / s;
    } else {
        float s = sqrtf(fmaxf(1.0f + r22 - r00 - r11, kEps)) * 2.0f;
        q0 = (r10 - r01) / s;
        q1 = (r02 + r20) / s;
        q2 = (r12 + r21) / s;
        q3 = 0.25f * s;
    }
    float qinv = rsqrtf(q0 * q0 + q1 * q1 + q2 * q2 + q3 * q3 + 1e-12f);
    q0 *= qinv; q1 *= qinv; q2 *= qinv; q3 *= qinv;

    size_t ro = ((size_t)b * kV + v) * 2;
    rec[ro + 0] = make_float4(me.x, me.y, me.z, 0.0f);
    rec[ro + 1] = make_float4(q0, q1, q2, q3);
}

// ---------------------------------------------------------------------------
// FUSED finalize (NPT=4) with NON-TEMPORAL stores: outputs bypass L2 so the
// rec gather working set (3.2MB/XCD) stays resident.
// ---------------------------------------------------------------------------
__global__ void finalize_all_kernel(const float4* __restrict__ rec,
                                    const int* __restrict__ vidx,
                                    const float* __restrict__ poff,
                                    const float* __restrict__ quat,
                                    const float* __restrict__ craw,
                                    const float* __restrict__ oraw,
                                    const float* __restrict__ lsc,
                                    float* __restrict__ out) {
    int b = blockIdx.x;
    int qi = blockIdx.y * blockDim.x + threadIdx.x;
    if (qi >= kN / 4) return;
    int n0 = qi * 4;

    int4 vi = *(const int4*)(vidx + n0);
    const float4* rb = rec + (size_t)b * kV * 2;

    float4 p[4], fq[4];
    p[0] = rb[(size_t)vi.x * 2]; fq[0] = rb[(size_t)vi.x * 2 + 1];
    p[1] = rb[(size_t)vi.y * 2]; fq[1] = rb[(size_t)vi.y * 2 + 1];
    p[2] = rb[(size_t)vi.z * 2]; fq[2] = rb[(size_t)vi.z * 2 + 1];
    p[3] = rb[(size_t)vi.w * 2]; fq[3] = rb[(size_t)vi.w * 2 + 1];

    const float4* po = (const float4*)(poff + (size_t)n0 * 3);
    float4 oa = po[0], ob = po[1], oc = po[2];
    float off[4][3] = {{oa.x, oa.y, oa.z}, {oa.w, ob.x, ob.y},
                       {ob.z, ob.w, oc.x}, {oc.y, oc.z, oc.w}};

    const float4* lq4 = (const float4*)(quat + (size_t)n0 * 4);

    float m[4][3];
    float4 rotv[4];
#pragma unroll
    for (int k = 0; k < 4; ++k) {
        float w = fq[k].x, x = fq[k].y, y = fq[k].z, z = fq[k].w;
        float tx = 1.0f - 2.0f * (y * y + z * z);
        float ty = 2.0f * (x * y + w * z);
        float tz = 2.0f * (x * z - w * y);
        float btx = 2.0f * (x * y - w * z);
        float bty = 1.0f - 2.0f * (x * x + z * z);
        float btz = 2.0f * (y * z + w * x);
        float nx = 2.0f * (x * z + w * y);
        float ny = 2.0f * (y * z - w * x);
        float nz = 1.0f - 2.0f * (x * x + y * y);

        float o0 = off[k][0], o1 = off[k][1], o2 = off[k][2];
        m[k][0] = p[k].x + o0 * tx + o1 * btx + o2 * nx;
        m[k][1] = p[k].y + o0 * ty + o1 * bty + o2 * ny;
        m[k][2] = p[k].z + o0 * tz + o1 * btz + o2 * nz;

        float4 lq = lq4[k];
        float lw = lq.x, lx = lq.y, ly = lq.z, lz = lq.w;
        float linv = rsqrtf(lw * lw + lx * lx + ly * ly + lz * lz + 1e-12f);
        lw *= linv; lx *= linv; ly *= linv; lz *= linv;

        rotv[k] = make_float4(w * lw - x * lx - y * ly - z * lz,
                              w * lx + x * lw + y * lz - z * ly,
                              w * ly - x * lz + y * lw + z * lx,
                              w * lz + x * ly - y * lx + z * lw);
    }

    const float4* cr4 = (const float4*)(craw + (size_t)n0 * 3);
    float4 ca = cr4[0], cb = cr4[1], cc = cr4[2];
    float4 ov = *(const float4*)(oraw + n0);
    const float4* ls4 = (const float4*)(lsc + (size_t)n0 * 3);
    float4 la = ls4[0], lb = ls4[1], lc = ls4[2];

    float4 sa = make_float4(sigm(ca.x), sigm(ca.y), sigm(ca.z), sigm(ca.w));
    float4 sb = make_float4(sigm(cb.x), sigm(cb.y), sigm(cb.z), sigm(cb.w));
    float4 sc = make_float4(sigm(cc.x), sigm(cc.y), sigm(cc.z), sigm(cc.w));
    float4 so = make_float4(sigm(ov.x), sigm(ov.y), sigm(ov.z), sigm(ov.w));
    float4 ea = make_float4(eclip(la.x), eclip(la.y), eclip(la.z), eclip(la.w));
    float4 eb = make_float4(eclip(lb.x), eclip(lb.y), eclip(lb.z), eclip(lb.w));
    float4 ec = make_float4(eclip(lc.x), eclip(lc.y), eclip(lc.z), eclip(lc.w));

    size_t bn0 = (size_t)b * kN + n0;
    float* mo = out + OFF_MEANS + bn0 * 3;
    nt_store4(mo + 0, m[0][0], m[0][1], m[0][2], m[1][0]);
    nt_store4(mo + 4, m[1][1], m[1][2], m[2][0], m[2][1]);
    nt_store4(mo + 8, m[2][2], m[3][0], m[3][1], m[3][2]);
    float* ro = out + OFF_ROT + bn0 * 4;
    nt_store4v(ro + 0,  rotv[0]);
    nt_store4v(ro + 4,  rotv[1]);
    nt_store4v(ro + 8,  rotv[2]);
    nt_store4v(ro + 12, rotv[3]);
    float* co = out + OFF_COLORS + bn0 * 3;
    nt_store4v(co + 0, sa);
    nt_store4v(co + 4, sb);
    nt_store4v(co + 8, sc);
    nt_store4v(out + OFF_OPAC + bn0, so);
    float* sco = out + OFF_SCALE + bn0 * 3;
    nt_store4v(sco + 0, ea);
    nt_store4v(sco + 4, eb);
    nt_store4v(sco + 8, ec);
}

// ---------------------------------------------------------------------------
// Fallback (R10): separate mr4 + cos with rec in d_out regions.
// ---------------------------------------------------------------------------
__global__ void finalize_mr4_kernel(const float4* __restrict__ rec,
                                    const int* __restrict__ vidx,
                                    const float* __restrict__ poff,
                                    const float* __restrict__ quat,
                                    float* __restrict__ out) {
    int b = blockIdx.x;
    int qi = blockIdx.y * blockDim.x + threadIdx.x;
    if (qi >= kN / 4) return;
    int n0 = qi * 4;

    int4 vi = *(const int4*)(vidx + n0);
    const float4* rb = rec + (size_t)b * kV * 2;

    float4 p[4], fq[4];
    p[0] = rb[(size_t)vi.x * 2]; fq[0] = rb[(size_t)vi.x * 2 + 1];
    p[1] = rb[(size_t)vi.y * 2]; fq[1] = rb[(size_t)vi.y * 2 + 1];
    p[2] = rb[(size_t)vi.z * 2]; fq[2] = rb[(size_t)vi.z * 2 + 1];
    p[3] = rb[(size_t)vi.w * 2]; fq[3] = rb[(size_t)vi.w * 2 + 1];

    const float4* po = (const float4*)(poff + (size_t)n0 * 3);
    float4 oa = po[0], ob = po[1], oc = po[2];
    float off[4][3] = {{oa.x, oa.y, oa.z}, {oa.w, ob.x, ob.y},
                       {ob.z, ob.w, oc.x}, {oc.y, oc.z, oc.w}};

    const float4* lq4 = (const float4*)(quat + (size_t)n0 * 4);

    float m[4][3];
    float4 rotv[4];
#pragma unroll
    for (int k = 0; k < 4; ++k) {
        float w = fq[k].x, x = fq[k].y, y = fq[k].z, z = fq[k].w;
        float tx = 1.0f - 2.0f * (y * y + z * z);
        float ty = 2.0f * (x * y + w * z);
        float tz = 2.0f * (x * z - w * y);
        float btx = 2.0f * (x * y - w * z);
        float bty = 1.0f - 2.0f * (x * x + z * z);
        float btz = 2.0f * (y * z + w * x);
        float nx = 2.0f * (x * z + w * y);
        float ny = 2.0f * (y * z - w * x);
        float nz = 1.0f - 2.0f * (x * x + y * y);

        float o0 = off[k][0], o1 = off[k][1], o2 = off[k][2];
        m[k][0] = p[k].x + o0 * tx + o1 * btx + o2 * nx;
        m[k][1] = p[k].y + o0 * ty + o1 * bty + o2 * ny;
        m[k][2] = p[k].z + o0 * tz + o1 * btz + o2 * nz;

        float4 lq = lq4[k];
        float lw = lq.x, lx = lq.y, ly = lq.z, lz = lq.w;
        float linv = rsqrtf(lw * lw + lx * lx + ly * ly + lz * lz + 1e-12f);
        lw *= linv; lx *= linv; ly *= linv; lz *= linv;

        rotv[k] = make_float4(w * lw - x * lx - y * ly - z * lz,
                              w * lx + x * lw + y * lz - z * ly,
                              w * ly - x * lz + y * lw + z * lx,
                              w * lz + x * ly - y * lx + z * lw);
    }

    size_t bn0 = (size_t)b * kN + n0;
    float4* mo = (float4*)(out + OFF_MEANS + bn0 * 3);
    mo[0] = make_float4(m[0][0], m[0][1], m[0][2], m[1][0]);
    mo[1] = make_float4(m[1][1], m[1][2], m[2][0], m[2][1]);
    mo[2] = make_float4(m[2][2], m[3][0], m[3][1], m[3][2]);
    float4* ro = (float4*)(out + OFF_ROT + bn0 * 4);
    ro[0] = rotv[0]; ro[1] = rotv[1]; ro[2] = rotv[2]; ro[3] = rotv[3];
}

__global__ void finalize_cos_kernel(const float* __restrict__ craw,
                                    const float* __restrict__ oraw,
                                    const float* __restrict__ lsc,
                                    float* __restrict__ out) {
    int b = blockIdx.x;
    int q = blockIdx.y * blockDim.x + threadIdx.x;
    if (q >= kN / 4) return;
    int n0 = q * 4;

    const float4* cr4 = (const float4*)(craw + (size_t)n0 * 3);
    float4 ca = cr4[0], cb = cr4[1], cc = cr4[2];
    float4 ov = *(const float4*)(oraw + n0);
    const float4* ls4 = (const float4*)(lsc + (size_t)n0 * 3);
    float4 la = ls4[0], lb = ls4[1], lc = ls4[2];

    float4 sa = make_float4(sigm(ca.x), sigm(ca.y), sigm(ca.z), sigm(ca.w));
    float4 sb = make_float4(sigm(cb.x), sigm(cb.y), sigm(cb.z), sigm(cb.w));
    float4 sc = make_float4(sigm(cc.x), sigm(cc.y), sigm(cc.z), sigm(cc.w));
    float4 so = make_float4(sigm(ov.x), sigm(ov.y), sigm(ov.z), sigm(ov.w));
    float4 ea = make_float4(eclip(la.x), eclip(la.y), eclip(la.z), eclip(la.w));
    float4 eb = make_float4(eclip(lb.x), eclip(lb.y), eclip(lb.z), eclip(lb.w));
    float4 ec = make_float4(eclip(lc.x), eclip(lc.y), eclip(lc.z), eclip(lc.w));

    size_t bn0 = (size_t)b * kN + n0;
    float4* co = (float4*)(out + OFF_COLORS + bn0 * 3);
    co[0] = sa; co[1] = sb; co[2] = sc;
    *(float4*)(out + OFF_OPAC + bn0) = so;
    float4* sco = (float4*)(out + OFF_SCALE + bn0 * 3);
    sco[0] = ea; sco[1] = eb; sco[2] = ec;
}

extern "C" void kernel_launch(void* const* d_in, const int* in_sizes, int n_in,
                              void* d_out, int out_size, void* d_ws, size_t ws_size,
                              hipStream_t stream) {
    const float* pose  = (const float*)d_in[0];
    const float* trans = (const float*)d_in[1];
    const float* scale = (const float*)d_in[2];
    const float* vt    = (const float*)d_in[3];
    const float* sw    = (const float*)d_in[4];
    const float* jr    = (const float*)d_in[5];
    const float* poff  = (const float*)d_in[6];
    const float* craw  = (const float*)d_in[7];
    const float* oraw  = (const float*)d_in[8];
    const float* lsc   = (const float*)d_in[9];
    const float* quat  = (const float*)d_in[10];
    const int*   vidx  = (const int*)d_in[11];
    const int*   faces = (const int*)d_in[12];
    float* out = (float*)d_out;
    char* ws = (char*)d_ws;

    float*        A   = (float*)(ws + WS_A);
    int*          cnt = (int*)(ws + WS_CNT);
    unsigned int* tri = (unsigned int*)(ws + WS_TRI);

    dim3 gV(kB, (kV + 255) / 256);
    dim3 gQ(kB, (kN / 4 + 255) / 256);

    zero_cnt_kernel<<<(kV + 255) / 256, 256, 0, stream>>>(cnt);
    fill_bucket_kernel<<<(kF + 255) / 256, 256, 0, stream>>>(faces, cnt, tri);
    jt_kernel<<<1, 64, 0, stream>>>(pose, jr, A);

    if (ws_size >= WS_END) {
        float4* rec = (float4*)(ws + WS_REC);
        float4* Vw  = (float4*)(ws + WS_VW);

        skin_kernel<<<gV, 256, 0, stream>>>(A, sw, vt, scale, trans, Vw);
        frame_kernel<<<gV, 256, 0, stream>>>(Vw, cnt, tri, rec);
        finalize_all_kernel<<<gQ, 256, 0, stream>>>(rec, vidx, poff, quat,
                                                    craw, oraw, lsc, out);
    } else {
        float4* rec = (float4*)(out + OFF_OPAC);
        float4* Vw  = (float4*)(out + OFF_SCALE);

        skin_kernel<<<gV, 256, 0, stream>>>(A, sw, vt, scale, trans, Vw);
        frame_kernel<<<gV, 256, 0, stream>>>(Vw, cnt, tri, rec);
        finalize_mr4_kernel<<<gQ, 256, 0, stream>>>(rec, vidx, poff, quat, out);
        finalize_cos_kernel<<<gQ, 256, 0, stream>>>(craw, oraw, lsc, out);
    }
}

// Round 19
// 251.247 us; speedup vs baseline: 1.3506x; 1.3506x over previous
//
#include <hip/hip_runtime.h>
#include <hip/hip_fp16.h>
#include <math.h>

// GaussianAvatar R19 = R16 (267.8us best) + ONE change: rec packed to 16B
// (8xf16: pos.xyz + pad + quat) = one uint4 gather per gaussian instead of
// two float4s. R17/R18 counters: finalize is fetch-bound on rec gathers
// (FETCH 255MB, ~0% L2 hit; nt-stores halved FETCH but write-amplified).
// Halving records and footprint (1.6MB/XCD) attacks the same mechanism on
// the read side. f16 error (5e-4 rel) is below the output's bf16
// quantization (absmax 0.03125 = bf16 rounding; threshold 0.16125).
namespace {
constexpr int kB = 32;
constexpr int kV = 25000;
constexpr int kJ = 20;
constexpr int kF = 50000;
constexpr int kN = 200000;
constexpr int kCap = 40;

constexpr float kEps = 1e-8f;

constexpr size_t OFF_MEANS  = 0;
constexpr size_t OFF_COLORS = (size_t)kB * kN * 3;
constexpr size_t OFF_OPAC   = OFF_COLORS + (size_t)kB * kN * 3;
constexpr size_t OFF_SCALE  = OFF_OPAC + (size_t)kB * kN;
constexpr size_t OFF_ROT    = OFF_SCALE + (size_t)kB * kN * 3;

// workspace layout (bytes)
constexpr size_t WS_A    = 0;
constexpr size_t WS_CNT  = 32768;
constexpr size_t WS_TRI  = 262144;               // kCap*kV uint = 4MB
constexpr size_t WS_REC  = 4325376;              // B*V uint4 = 12.8MB
constexpr size_t WS_VW   = WS_REC + 12800000;    // B*V float4 = 12.8MB
constexpr size_t WS_END  = WS_VW + 12800000;     // ~30MB
}

__device__ __forceinline__ float sigm(float x) {
    return 1.0f / (1.0f + __expf(-x));
}
__device__ __forceinline__ float eclip(float x) {
    return fminf(fmaxf(__expf(x), 0.0005f), 0.05f);
}

__device__ __forceinline__ unsigned int pack2h(float a, float b) {
    unsigned short ha = __half_as_ushort(__float2half_rn(a));
    unsigned short hb = __half_as_ushort(__float2half_rn(b));
    return (unsigned int)ha | ((unsigned int)hb << 16);
}
__device__ __forceinline__ float2 unpack2h(unsigned int u) {
    float a = __half2float(__ushort_as_half((unsigned short)(u & 0xffffu)));
    float b = __half2float(__ushort_as_half((unsigned short)(u >> 16)));
    return make_float2(a, b);
}

// ---------------------------------------------------------------------------
__global__ void zero_cnt_kernel(int* __restrict__ cnt) {
    int i = blockIdx.x * blockDim.x + threadIdx.x;
    if (i < kV) cnt[i] = 0;
}

// ---------------------------------------------------------------------------
// Bucket fill: tri[slot][v] = ia | ib<<15 | swap<<30 (v is base corner;
// swap=k==1 preserves orientation).
// ---------------------------------------------------------------------------
__global__ void fill_bucket_kernel(const int* __restrict__ faces,
                                   int* __restrict__ cursor,
                                   unsigned int* __restrict__ tri) {
    int f = blockIdx.x * blockDim.x + threadIdx.x;
    if (f >= kF) return;
    int i0 = faces[f * 3 + 0];
    int i1 = faces[f * 3 + 1];
    int i2 = faces[f * 3 + 2];
    const int vs[3] = {i0, i1, i2};
#pragma unroll
    for (int k = 0; k < 3; ++k) {
        int v = vs[k];
        unsigned int ia = (k == 0) ? (unsigned)i1 : (unsigned)i0;
        unsigned int ib = (k == 2) ? (unsigned)i1 : (unsigned)i2;
        unsigned int swap = (k == 1) ? 1u : 0u;
        unsigned int rec = ia | (ib << 15) | (swap << 30);
        int p = atomicAdd(&cursor[v], 1);
        if (p < kCap) tri[(size_t)p * kV + v] = rec;  // slot-major
    }
}

// ---------------------------------------------------------------------------
__global__ void jt_kernel(const float* __restrict__ pose,
                          const float* __restrict__ jr,
                          float* __restrict__ A) {
    int b = threadIdx.x;
    if (b >= kB) return;

    float Gr[9], Gt[3];
    for (int j = 0; j < kJ; ++j) {
        float ax = pose[b * (kJ * 3) + j * 3 + 0];
        float ay = pose[b * (kJ * 3) + j * 3 + 1];
        float az = pose[b * (kJ * 3) + j * 3 + 2];
        float t2 = ax * ax + ay * ay + az * az + 1e-12f;
        float th = sqrtf(t2);
        float inv = 1.0f / th;
        float ux = ax * inv, uy = ay * inv, uz = az * inv;
        float s = sinf(th), c = cosf(th), oc = 1.0f - c;
        float R[9];
        R[0] = 1.0f + oc * (-(uy * uy + uz * uz));
        R[1] = -s * uz + oc * (ux * uy);
        R[2] =  s * uy + oc * (ux * uz);
        R[3] =  s * uz + oc * (ux * uy);
        R[4] = 1.0f + oc * (-(ux * ux + uz * uz));
        R[5] = -s * ux + oc * (uy * uz);
        R[6] = -s * uy + oc * (ux * uz);
        R[7] =  s * ux + oc * (uy * uz);
        R[8] = 1.0f + oc * (-(ux * ux + uy * uy));

        float jx = jr[j * 3 + 0], jy = jr[j * 3 + 1], jz = jr[j * 3 + 2];

        if (j == 0) {
            for (int k = 0; k < 9; ++k) Gr[k] = R[k];
            Gt[0] = jx; Gt[1] = jy; Gt[2] = jz;
        } else {
            float pjx = jr[(j - 1) * 3 + 0];
            float pjy = jr[(j - 1) * 3 + 1];
            float pjz = jr[(j - 1) * 3 + 2];
            float ltx = jx - pjx, lty = jy - pjy, ltz = jz - pjz;
            float nR[9], nT[3];
            for (int r = 0; r < 3; ++r) {
                float g0 = Gr[r * 3 + 0], g1 = Gr[r * 3 + 1], g2 = Gr[r * 3 + 2];
                nR[r * 3 + 0] = g0 * R[0] + g1 * R[3] + g2 * R[6];
                nR[r * 3 + 1] = g0 * R[1] + g1 * R[4] + g2 * R[7];
                nR[r * 3 + 2] = g0 * R[2] + g1 * R[5] + g2 * R[8];
                nT[r] = g0 * ltx + g1 * lty + g2 * ltz + Gt[r];
            }
            for (int k = 0; k < 9; ++k) Gr[k] = nR[k];
            Gt[0] = nT[0]; Gt[1] = nT[1]; Gt[2] = nT[2];
        }

        float tgx = Gt[0] - (Gr[0] * jx + Gr[1] * jy + Gr[2] * jz);
        float tgy = Gt[1] - (Gr[3] * jx + Gr[4] * jy + Gr[5] * jz);
        float tgz = Gt[2] - (Gr[6] * jx + Gr[7] * jy + Gr[8] * jz);
        float* Ao = A + ((size_t)b * kJ + j) * 12;
        Ao[0] = Gr[0]; Ao[1] = Gr[1]; Ao[2]  = Gr[2]; Ao[3]  = tgx;
        Ao[4] = Gr[3]; Ao[5] = Gr[4]; Ao[6]  = Gr[5]; Ao[7]  = tgy;
        Ao[8] = Gr[6]; Ao[9] = Gr[7]; Ao[10] = Gr[8]; Ao[11] = tgz;
    }
}

// ---------------------------------------------------------------------------
// Kernel 2: LBS skinning. b = blockIdx.x (XCD = b%8).
// ---------------------------------------------------------------------------
__global__ void skin_kernel(const float* __restrict__ A,
                            const float* __restrict__ sw,
                            const float* __restrict__ vt,
                            const float* __restrict__ scale,
                            const float* __restrict__ trans,
                            float4* __restrict__ Vw) {
    int b = blockIdx.x;
    int v = blockIdx.y * blockDim.x + threadIdx.x;
    __shared__ float sA[kJ * 12];
    if (threadIdx.x < kJ * 12) sA[threadIdx.x] = A[(size_t)b * kJ * 12 + threadIdx.x];
    __syncthreads();
    if (v >= kV) return;

    const float4* sw4 = (const float4*)(sw + (size_t)v * kJ);
    float w[kJ];
#pragma unroll
    for (int q = 0; q < 5; ++q) {
        float4 f = sw4[q];
        w[q * 4 + 0] = f.x; w[q * 4 + 1] = f.y;
        w[q * 4 + 2] = f.z; w[q * 4 + 3] = f.w;
    }

    float T[12];
#pragma unroll
    for (int k = 0; k < 12; ++k) T[k] = 0.0f;
#pragma unroll
    for (int j = 0; j < kJ; ++j) {
        float wj = w[j];
#pragma unroll
        for (int k = 0; k < 12; ++k) T[k] += wj * sA[j * 12 + k];
    }
    float x = vt[v * 3 + 0], y = vt[v * 3 + 1], z = vt[v * 3 + 2];
    float px = T[0] * x + T[1] * y + T[2]  * z + T[3];
    float py = T[4] * x + T[5] * y + T[6]  * z + T[7];
    float pz = T[8] * x + T[9] * y + T[10] * z + T[11];
    float s = scale[b];
    float tx = trans[b * 3 + 0], ty = trans[b * 3 + 1], tz = trans[b * 3 + 2];
    Vw[(size_t)b * kV + v] = make_float4(px * s + tx, py * s + ty, pz * s + tz, 0.0f);
}

// ---------------------------------------------------------------------------
// Kernel 3: frame + quat; v is always the base corner (2 gathers/face).
// Writes ONE 16B packed record: {px,py | pz,0 | q0,q1 | q2,q3} as 8xf16.
// ---------------------------------------------------------------------------
__global__ void frame_kernel(const float4* __restrict__ Vw,
                             const int* __restrict__ cnt,
                             const unsigned int* __restrict__ tri,
                             uint4* __restrict__ rec) {
    int b = blockIdx.x;
    int v = blockIdx.y * blockDim.x + threadIdx.x;
    if (v >= kV) return;
    const float4* base = Vw + (size_t)b * kV;
    float4 me = base[v];

    int deg = min(cnt[v], kCap);
    float sx = 0.0f, sy = 0.0f, sz = 0.0f;
    for (int i = 0; i < deg; ++i) {
        unsigned int r = tri[(size_t)i * kV + v];
        int ia = (int)(r & 0x7fffu);
        int ib = (int)((r >> 15) & 0x7fffu);
        bool swap = (r >> 30) != 0u;
        int j1 = swap ? ib : ia;
        int j2 = swap ? ia : ib;
        float4 c1 = base[j1];
        float4 c2 = base[j2];
        float e1x = c1.x - me.x, e1y = c1.y - me.y, e1z = c1.z - me.z;
        float e2x = c2.x - me.x, e2y = c2.y - me.y, e2z = c2.z - me.z;
        sx += e1y * e2z - e1z * e2y;
        sy += e1z * e2x - e1x * e2z;
        sz += e1x * e2y - e1y * e2x;
    }

    float ninv = rsqrtf(sx * sx + sy * sy + sz * sz + 1e-12f);
    float nx = sx * ninv, ny = sy * ninv, nz = sz * ninv;

    bool small = fabsf(nx) < 0.9f;
    float refx = small ? 1.0f : 0.0f;
    float refz = small ? 0.0f : 1.0f;
    float d = refx * nx + refz * nz;
    float tx0 = refx - d * nx, ty0 = -d * ny, tz0 = refz - d * nz;
    float tinv = rsqrtf(tx0 * tx0 + ty0 * ty0 + tz0 * tz0 + 1e-12f);
    float tx = tx0 * tinv, ty = ty0 * tinv, tz = tz0 * tinv;

    float btx = ny * tz - nz * ty;
    float bty = nz * tx - nx * tz;
    float btz = nx * ty - ny * tx;

    float r00 = tx, r01 = btx, r02 = nx;
    float r10 = ty, r11 = bty, r12 = ny;
    float r20 = tz, r21 = btz, r22 = nz;
    float tr = r00 + r11 + r22;
    float q0, q1, q2, q3;
    if (tr > 0.0f) {
        float s = sqrtf(fmaxf(tr + 1.0f, kEps)) * 2.0f;
        q0 = 0.25f * s;
        q1 = (r21 - r12) / s;
        q2 = (r02 - r20) / s;
        q3 = (r10 - r01) / s;
    } else if (r00 > r11 && r00 > r22) {
        float s = sqrtf(fmaxf(1.0f + r00 - r11 - r22, kEps)) * 2.0f;
        q0 = (r21 - r12) / s;
        q1 = 0.25f * s;
        q2 = (r01 + r10) / s;
        q3 = (r02 + r20) / s;
    } else if (r11 > r22) {
        float s = sqrtf(fmaxf(1.0f + r11 - r00 - r22, kEps)) * 2.0f;
        q0 = (r02 - r20) / s;
        q1 = (r01 + r10) / s;
        q2 = 0.25f * s;
        q3 = (r12 + r21) / s;
    } else {
        float s = sqrtf(fmaxf(1.0f + r22 - r00 - r11, kEps)) * 2.0f;
        q0 = (r10 - r01) / s;
        q1 = (r02 + r20) / s;
        q2 = (r12 + r21) / s;
        q3 = 0.25f * s;
    }
    float qinv = rsqrtf(q0 * q0 + q1 * q1 + q2 * q2 + q3 * q3 + 1e-12f);
    q0 *= qinv; q1 *= qinv; q2 *= qinv; q3 *= qinv;

    uint4 r16;
    r16.x = pack2h(me.x, me.y);
    r16.y = pack2h(me.z, 0.0f);
    r16.z = pack2h(q0, q1);
    r16.w = pack2h(q2, q3);
    rec[(size_t)b * kV + v] = r16;
}

// ---------------------------------------------------------------------------
// FUSED finalize (NPT=4): ONE uint4 gather per gaussian (16B packed record).
// ---------------------------------------------------------------------------
__global__ void finalize_all_kernel(const uint4* __restrict__ rec,
                                    const int* __restrict__ vidx,
                                    const float* __restrict__ poff,
                                    const float* __restrict__ quat,
                                    const float* __restrict__ craw,
                                    const float* __restrict__ oraw,
                                    const float* __restrict__ lsc,
                                    float* __restrict__ out) {
    int b = blockIdx.x;
    int qi = blockIdx.y * blockDim.x + threadIdx.x;
    if (qi >= kN / 4) return;
    int n0 = qi * 4;

    int4 vi = *(const int4*)(vidx + n0);
    const uint4* rb = rec + (size_t)b * kV;

    uint4 r[4];
    r[0] = rb[vi.x];
    r[1] = rb[vi.y];
    r[2] = rb[vi.z];
    r[3] = rb[vi.w];

    const float4* po = (const float4*)(poff + (size_t)n0 * 3);
    float4 oa = po[0], ob = po[1], oc = po[2];
    float off[4][3] = {{oa.x, oa.y, oa.z}, {oa.w, ob.x, ob.y},
                       {ob.z, ob.w, oc.x}, {oc.y, oc.z, oc.w}};

    const float4* lq4 = (const float4*)(quat + (size_t)n0 * 4);

    float m[4][3];
    float4 rotv[4];
#pragma unroll
    for (int k = 0; k < 4; ++k) {
        float2 pxy = unpack2h(r[k].x);
        float2 pz_ = unpack2h(r[k].y);
        float2 q01 = unpack2h(r[k].z);
        float2 q23 = unpack2h(r[k].w);
        float w = q01.x, x = q01.y, y = q23.x, z = q23.y;

        float tx = 1.0f - 2.0f * (y * y + z * z);
        float ty = 2.0f * (x * y + w * z);
        float tz = 2.0f * (x * z - w * y);
        float btx = 2.0f * (x * y - w * z);
        float bty = 1.0f - 2.0f * (x * x + z * z);
        float btz = 2.0f * (y * z + w * x);
        float nx = 2.0f * (x * z + w * y);
        float ny = 2.0f * (y * z - w * x);
        float nz = 1.0f - 2.0f * (x * x + y * y);

        float o0 = off[k][0], o1 = off[k][1], o2 = off[k][2];
        m[k][0] = pxy.x + o0 * tx + o1 * btx + o2 * nx;
        m[k][1] = pxy.y + o0 * ty + o1 * bty + o2 * ny;
        m[k][2] = pz_.x + o0 * tz + o1 * btz + o2 * nz;

        float4 lq = lq4[k];
        float lw = lq.x, lx = lq.y, ly = lq.z, lz = lq.w;
        float linv = rsqrtf(lw * lw + lx * lx + ly * ly + lz * lz + 1e-12f);
        lw *= linv; lx *= linv; ly *= linv; lz *= linv;

        rotv[k] = make_float4(w * lw - x * lx - y * ly - z * lz,
                              w * lx + x * lw + y * lz - z * ly,
                              w * ly - x * lz + y * lw + z * lx,
                              w * lz + x * ly - y * lx + z * lw);
    }

    const float4* cr4 = (const float4*)(craw + (size_t)n0 * 3);
    float4 ca = cr4[0], cb = cr4[1], cc = cr4[2];
    float4 ov = *(const float4*)(oraw + n0);
    const float4* ls4 = (const float4*)(lsc + (size_t)n0 * 3);
    float4 la = ls4[0], lb = ls4[1], lc = ls4[2];

    float4 sa = make_float4(sigm(ca.x), sigm(ca.y), sigm(ca.z), sigm(ca.w));
    float4 sb = make_float4(sigm(cb.x), sigm(cb.y), sigm(cb.z), sigm(cb.w));
    float4 sc = make_float4(sigm(cc.x), sigm(cc.y), sigm(cc.z), sigm(cc.w));
    float4 so = make_float4(sigm(ov.x), sigm(ov.y), sigm(ov.z), sigm(ov.w));
    float4 ea = make_float4(eclip(la.x), eclip(la.y), eclip(la.z), eclip(la.w));
    float4 eb = make_float4(eclip(lb.x), eclip(lb.y), eclip(lb.z), eclip(lb.w));
    float4 ec = make_float4(eclip(lc.x), eclip(lc.y), eclip(lc.z), eclip(lc.w));

    size_t bn0 = (size_t)b * kN + n0;
    float4* mo = (float4*)(out + OFF_MEANS + bn0 * 3);
    mo[0] = make_float4(m[0][0], m[0][1], m[0][2], m[1][0]);
    mo[1] = make_float4(m[1][1], m[1][2], m[2][0], m[2][1]);
    mo[2] = make_float4(m[2][2], m[3][0], m[3][1], m[3][2]);
    float4* ro = (float4*)(out + OFF_ROT + bn0 * 4);
    ro[0] = rotv[0]; ro[1] = rotv[1]; ro[2] = rotv[2]; ro[3] = rotv[3];
    float4* co = (float4*)(out + OFF_COLORS + bn0 * 3);
    co[0] = sa; co[1] = sb; co[2] = sc;
    *(float4*)(out + OFF_OPAC + bn0) = so;
    float4* sco = (float4*)(out + OFF_SCALE + bn0 * 3);
    sco[0] = ea; sco[1] = eb; sco[2] = ec;
}

// ---------------------------------------------------------------------------
// Fallback kernels (ws too small): R10 structure with f32 rec in d_out.
// ---------------------------------------------------------------------------
__global__ void frame_f32_kernel(const float4* __restrict__ Vw,
                                 const int* __restrict__ cnt,
                                 const unsigned int* __restrict__ tri,
                                 float4* __restrict__ rec) {
    int b = blockIdx.x;
    int v = blockIdx.y * blockDim.x + threadIdx.x;
    if (v >= kV) return;
    const float4* base = Vw + (size_t)b * kV;
    float4 me = base[v];

    int deg = min(cnt[v], kCap);
    float sx = 0.0f, sy = 0.0f, sz = 0.0f;
    for (int i = 0; i < deg; ++i) {
        unsigned int r = tri[(size_t)i * kV + v];
        int ia = (int)(r & 0x7fffu);
        int ib = (int)((r >> 15) & 0x7fffu);
        bool swap = (r >> 30) != 0u;
        int j1 = swap ? ib : ia;
        int j2 = swap ? ia : ib;
        float4 c1 = base[j1];
        float4 c2 = base[j2];
        float e1x = c1.x - me.x, e1y = c1.y - me.y, e1z = c1.z - me.z;
        float e2x = c2.x - me.x, e2y = c2.y - me.y, e2z = c2.z - me.z;
        sx += e1y * e2z - e1z * e2y;
        sy += e1z * e2x - e1x * e2z;
        sz += e1x * e2y - e1y * e2x;
    }

    float ninv = rsqrtf(sx * sx + sy * sy + sz * sz + 1e-12f);
    float nx = sx * ninv, ny = sy * ninv, nz = sz * ninv;

    bool small = fabsf(nx) < 0.9f;
    float refx = small ? 1.0f : 0.0f;
    float refz = small ? 0.0f : 1.0f;
    float d = refx * nx + refz * nz;
    float tx0 = refx - d * nx, ty0 = -d * ny, tz0 = refz - d * nz;
    float tinv = rsqrtf(tx0 * tx0 + ty0 * ty0 + tz0 * tz0 + 1e-12f);
    float tx = tx0 * tinv, ty = ty0 * tinv, tz = tz0 * tinv;

    float btx = ny * tz - nz * ty;
    float bty = nz * tx - nx * tz;
    float btz = nx * ty - ny * tx;

    float r00 = tx, r01 = btx, r02 = nx;
    float r10 = ty, r11 = bty, r12 = ny;
    float r20 = tz, r21 = btz, r22 = nz;
    float tr = r00 + r11 + r22;
    float q0, q1, q2, q3;
    if (tr > 0.0f) {
        float s = sqrtf(fmaxf(tr + 1.0f, kEps)) * 2.0f;
        q0 = 0.25f * s;
        q1 = (r21 - r12) / s;
        q2 = (r02 - r20) / s;
        q3 = (r10 - r01) / s;
    } else if (r00 > r11 && r00 > r22) {
        float s = sqrtf(fmaxf(1.0f + r00 - r11 - r22, kEps)) * 2.0f;
        q0 = (r21 - r12) / s;
        q1 = 0.25f * s;
        q2 = (r01 + r10) / s;
        q3 = (r02 + r20) / s;
    } else if (r11 > r22) {
        float s = sqrtf(fmaxf(1.0f + r11 - r00 - r22, kEps)) * 2.0f;
        q0 = (r02 - r20) / s;
        q1 = (r01 + r10) / s;
        q2 = 0.25f * s;
        q3 = (r12 + r21) / s;
    } else {
        float s = sqrtf(fmaxf(1.0f + r22 - r00 - r11, kEps)) * 2.0f;
        q0 = (r10 - r01) / s;
        q1 = (r02 + r20) / s;
        q2 = (r12 + r21) / s;
        q3 = 0.25f * s;
    }
    float qinv = rsqrtf(q0 * q0 + q1 * q1 + q2 * q2 + q3 * q3 + 1e-12f);
    q0 *= qinv; q1 *= qinv; q2 *= qinv; q3 *= qinv;

    size_t ro = ((size_t)b * kV + v) * 2;
    rec[ro + 0] = make_float4(me.x, me.y, me.z, 0.0f);
    rec[ro + 1] = make_float4(q0, q1, q2, q3);
}

__global__ void finalize_mr4_kernel(const float4* __restrict__ rec,
                                    const int* __restrict__ vidx,
                                    const float* __restrict__ poff,
                                    const float* __restrict__ quat,
                                    float* __restrict__ out) {
    int b = blockIdx.x;
    int qi = blockIdx.y * blockDim.x + threadIdx.x;
    if (qi >= kN / 4) return;
    int n0 = qi * 4;

    int4 vi = *(const int4*)(vidx + n0);
    const float4* rb = rec + (size_t)b * kV * 2;

    float4 p[4], fq[4];
    p[0] = rb[(size_t)vi.x * 2]; fq[0] = rb[(size_t)vi.x * 2 + 1];
    p[1] = rb[(size_t)vi.y * 2]; fq[1] = rb[(size_t)vi.y * 2 + 1];
    p[2] = rb[(size_t)vi.z * 2]; fq[2] = rb[(size_t)vi.z * 2 + 1];
    p[3] = rb[(size_t)vi.w * 2]; fq[3] = rb[(size_t)vi.w * 2 + 1];

    const float4* po = (const float4*)(poff + (size_t)n0 * 3);
    float4 oa = po[0], ob = po[1], oc = po[2];
    float off[4][3] = {{oa.x, oa.y, oa.z}, {oa.w, ob.x, ob.y},
                       {ob.z, ob.w, oc.x}, {oc.y, oc.z, oc.w}};

    const float4* lq4 = (const float4*)(quat + (size_t)n0 * 4);

    float m[4][3];
    float4 rotv[4];
#pragma unroll
    for (int k = 0; k < 4; ++k) {
        float w = fq[k].x, x = fq[k].y, y = fq[k].z, z = fq[k].w;
        float tx = 1.0f - 2.0f * (y * y + z * z);
        float ty = 2.0f * (x * y + w * z);
        float tz = 2.0f * (x * z - w * y);
        float btx = 2.0f * (x * y - w * z);
        float bty = 1.0f - 2.0f * (x * x + z * z);
        float btz = 2.0f * (y * z + w * x);
        float nx = 2.0f * (x * z + w * y);
        float ny = 2.0f * (y * z - w * x);
        float nz = 1.0f - 2.0f * (x * x + y * y);

        float o0 = off[k][0], o1 = off[k][1], o2 = off[k][2];
        m[k][0] = p[k].x + o0 * tx + o1 * btx + o2 * nx;
        m[k][1] = p[k].y + o0 * ty + o1 * bty + o2 * ny;
        m[k][2] = p[k].z + o0 * tz + o1 * btz + o2 * nz;

        float4 lq = lq4[k];
        float lw = lq.x, lx = lq.y, ly = lq.z, lz = lq.w;
        float linv = rsqrtf(lw * lw + lx * lx + ly * ly + lz * lz + 1e-12f);
        lw *= linv; lx *= linv; ly *= linv; lz *= linv;

        rotv[k] = make_float4(w * lw - x * lx - y * ly - z * lz,
                              w * lx + x * lw + y * lz - z * ly,
                              w * ly - x * lz + y * lw + z * lx,
                              w * lz + x * ly - y * lx + z * lw);
    }

    size_t bn0 = (size_t)b * kN + n0;
    float4* mo = (float4*)(out + OFF_MEANS + bn0 * 3);
    mo[0] = make_float4(m[0][0], m[0][1], m[0][2], m[1][0]);
    mo[1] = make_float4(m[1][1], m[1][2], m[2][0], m[2][1]);
    mo[2] = make_float4(m[2][2], m[3][0], m[3][1], m[3][2]);
    float4* ro = (float4*)(out + OFF_ROT + bn0 * 4);
    ro[0] = rotv[0]; ro[1] = rotv[1]; ro[2] = rotv[2]; ro[3] = rotv[3];
}

__global__ void finalize_cos_kernel(const float* __restrict__ craw,
                                    const float* __restrict__ oraw,
                                    const float* __restrict__ lsc,
                                    float* __restrict__ out) {
    int b = blockIdx.x;
    int q = blockIdx.y * blockDim.x + threadIdx.x;
    if (q >= kN / 4) return;
    int n0 = q * 4;

    const float4* cr4 = (const float4*)(craw + (size_t)n0 * 3);
    float4 ca = cr4[0], cb = cr4[1], cc = cr4[2];
    float4 ov = *(const float4*)(oraw + n0);
    const float4* ls4 = (const float4*)(lsc + (size_t)n0 * 3);
    float4 la = ls4[0], lb = ls4[1], lc = ls4[2];

    float4 sa = make_float4(sigm(ca.x), sigm(ca.y), sigm(ca.z), sigm(ca.w));
    float4 sb = make_float4(sigm(cb.x), sigm(cb.y), sigm(cb.z), sigm(cb.w));
    float4 sc = make_float4(sigm(cc.x), sigm(cc.y), sigm(cc.z), sigm(cc.w));
    float4 so = make_float4(sigm(ov.x), sigm(ov.y), sigm(ov.z), sigm(ov.w));
    float4 ea = make_float4(eclip(la.x), eclip(la.y), eclip(la.z), eclip(la.w));
    float4 eb = make_float4(eclip(lb.x), eclip(lb.y), eclip(lb.z), eclip(lb.w));
    float4 ec = make_float4(eclip(lc.x), eclip(lc.y), eclip(lc.z), eclip(lc.w));

    size_t bn0 = (size_t)b * kN + n0;
    float4* co = (float4*)(out + OFF_COLORS + bn0 * 3);
    co[0] = sa; co[1] = sb; co[2] = sc;
    *(float4*)(out + OFF_OPAC + bn0) = so;
    float4* sco = (float4*)(out + OFF_SCALE + bn0 * 3);
    sco[0] = ea; sco[1] = eb; sco[2] = ec;
}

extern "C" void kernel_launch(void* const* d_in, const int* in_sizes, int n_in,
                              void* d_out, int out_size, void* d_ws, size_t ws_size,
                              hipStream_t stream) {
    const float* pose  = (const float*)d_in[0];
    const float* trans = (const float*)d_in[1];
    const float* scale = (const float*)d_in[2];
    const float* vt    = (const float*)d_in[3];
    const float* sw    = (const float*)d_in[4];
    const float* jr    = (const float*)d_in[5];
    const float* poff  = (const float*)d_in[6];
    const float* craw  = (const float*)d_in[7];
    const float* oraw  = (const float*)d_in[8];
    const float* lsc   = (const float*)d_in[9];
    const float* quat  = (const float*)d_in[10];
    const int*   vidx  = (const int*)d_in[11];
    const int*   faces = (const int*)d_in[12];
    float* out = (float*)d_out;
    char* ws = (char*)d_ws;

    float*        A   = (float*)(ws + WS_A);
    int*          cnt = (int*)(ws + WS_CNT);
    unsigned int* tri = (unsigned int*)(ws + WS_TRI);

    dim3 gV(kB, (kV + 255) / 256);
    dim3 gQ(kB, (kN / 4 + 255) / 256);

    zero_cnt_kernel<<<(kV + 255) / 256, 256, 0, stream>>>(cnt);
    fill_bucket_kernel<<<(kF + 255) / 256, 256, 0, stream>>>(faces, cnt, tri);
    jt_kernel<<<1, 64, 0, stream>>>(pose, jr, A);

    if (ws_size >= WS_END) {
        uint4*  rec = (uint4*)(ws + WS_REC);
        float4* Vw  = (float4*)(ws + WS_VW);

        skin_kernel<<<gV, 256, 0, stream>>>(A, sw, vt, scale, trans, Vw);
        frame_kernel<<<gV, 256, 0, stream>>>(Vw, cnt, tri, rec);
        finalize_all_kernel<<<gQ, 256, 0, stream>>>(rec, vidx, poff, quat,
                                                    craw, oraw, lsc, out);
    } else {
        float4* rec = (float4*)(out + OFF_OPAC);
        float4* Vw  = (float4*)(out + OFF_SCALE);

        skin_kernel<<<gV, 256, 0, stream>>>(A, sw, vt, scale, trans, Vw);
        frame_f32_kernel<<<gV, 256, 0, stream>>>(Vw, cnt, tri, rec);
        finalize_mr4_kernel<<<gQ, 256, 0, stream>>>(rec, vidx, poff, quat, out);
        finalize_cos_kernel<<<gQ, 256, 0, stream>>>(craw, oraw, lsc, out);
    }
}

// Round 20
// 247.048 us; speedup vs baseline: 1.3736x; 1.0170x over previous
//
#include <hip/hip_runtime.h>
#include <hip/hip_fp16.h>
#include <math.h>

// GaussianAvatar R20 = R19 (251.2us best) + ONE change: non-temporal stores
// for the ROT output only. Rot is the only stream where each lane writes one
// aligned 16B quad (4 lanes = full 64B line) so nt cannot partial-line
// amplify (R18's failure mode); removes 102MB (28%) of L2 write allocations
// that evict the f16 rec gather set.
namespace {
constexpr int kB = 32;
constexpr int kV = 25000;
constexpr int kJ = 20;
constexpr int kF = 50000;
constexpr int kN = 200000;
constexpr int kCap = 40;

constexpr float kEps = 1e-8f;

constexpr size_t OFF_MEANS  = 0;
constexpr size_t OFF_COLORS = (size_t)kB * kN * 3;
constexpr size_t OFF_OPAC   = OFF_COLORS + (size_t)kB * kN * 3;
constexpr size_t OFF_SCALE  = OFF_OPAC + (size_t)kB * kN;
constexpr size_t OFF_ROT    = OFF_SCALE + (size_t)kB * kN * 3;

// workspace layout (bytes)
constexpr size_t WS_A    = 0;
constexpr size_t WS_CNT  = 32768;
constexpr size_t WS_TRI  = 262144;               // kCap*kV uint = 4MB
constexpr size_t WS_REC  = 4325376;              // B*V uint4 = 12.8MB
constexpr size_t WS_VW   = WS_REC + 12800000;    // B*V float4 = 12.8MB
constexpr size_t WS_END  = WS_VW + 12800000;     // ~30MB
}

__device__ __forceinline__ float sigm(float x) {
    return 1.0f / (1.0f + __expf(-x));
}
__device__ __forceinline__ float eclip(float x) {
    return fminf(fmaxf(__expf(x), 0.0005f), 0.05f);
}

__device__ __forceinline__ unsigned int pack2h(float a, float b) {
    unsigned short ha = __half_as_ushort(__float2half_rn(a));
    unsigned short hb = __half_as_ushort(__float2half_rn(b));
    return (unsigned int)ha | ((unsigned int)hb << 16);
}
__device__ __forceinline__ float2 unpack2h(unsigned int u) {
    float a = __half2float(__ushort_as_half((unsigned short)(u & 0xffffu)));
    float b = __half2float(__ushort_as_half((unsigned short)(u >> 16)));
    return make_float2(a, b);
}

// native clang vector for nontemporal builtins (16B, same layout as float4)
typedef float f4 __attribute__((ext_vector_type(4)));
__device__ __forceinline__ void nt_store4v(float* p, float4 v) {
    f4 t = {v.x, v.y, v.z, v.w};
    __builtin_nontemporal_store(t, (f4*)p);
}

// ---------------------------------------------------------------------------
__global__ void zero_cnt_kernel(int* __restrict__ cnt) {
    int i = blockIdx.x * blockDim.x + threadIdx.x;
    if (i < kV) cnt[i] = 0;
}

// ---------------------------------------------------------------------------
// Bucket fill: tri[slot][v] = ia | ib<<15 | swap<<30 (v is base corner;
// swap=k==1 preserves orientation).
// ---------------------------------------------------------------------------
__global__ void fill_bucket_kernel(const int* __restrict__ faces,
                                   int* __restrict__ cursor,
                                   unsigned int* __restrict__ tri) {
    int f = blockIdx.x * blockDim.x + threadIdx.x;
    if (f >= kF) return;
    int i0 = faces[f * 3 + 0];
    int i1 = faces[f * 3 + 1];
    int i2 = faces[f * 3 + 2];
    const int vs[3] = {i0, i1, i2};
#pragma unroll
    for (int k = 0; k < 3; ++k) {
        int v = vs[k];
        unsigned int ia = (k == 0) ? (unsigned)i1 : (unsigned)i0;
        unsigned int ib = (k == 2) ? (unsigned)i1 : (unsigned)i2;
        unsigned int swap = (k == 1) ? 1u : 0u;
        unsigned int rec = ia | (ib << 15) | (swap << 30);
        int p = atomicAdd(&cursor[v], 1);
        if (p < kCap) tri[(size_t)p * kV + v] = rec;  // slot-major
    }
}

// ---------------------------------------------------------------------------
__global__ void jt_kernel(const float* __restrict__ pose,
                          const float* __restrict__ jr,
                          float* __restrict__ A) {
    int b = threadIdx.x;
    if (b >= kB) return;

    float Gr[9], Gt[3];
    for (int j = 0; j < kJ; ++j) {
        float ax = pose[b * (kJ * 3) + j * 3 + 0];
        float ay = pose[b * (kJ * 3) + j * 3 + 1];
        float az = pose[b * (kJ * 3) + j * 3 + 2];
        float t2 = ax * ax + ay * ay + az * az + 1e-12f;
        float th = sqrtf(t2);
        float inv = 1.0f / th;
        float ux = ax * inv, uy = ay * inv, uz = az * inv;
        float s = sinf(th), c = cosf(th), oc = 1.0f - c;
        float R[9];
        R[0] = 1.0f + oc * (-(uy * uy + uz * uz));
        R[1] = -s * uz + oc * (ux * uy);
        R[2] =  s * uy + oc * (ux * uz);
        R[3] =  s * uz + oc * (ux * uy);
        R[4] = 1.0f + oc * (-(ux * ux + uz * uz));
        R[5] = -s * ux + oc * (uy * uz);
        R[6] = -s * uy + oc * (ux * uz);
        R[7] =  s * ux + oc * (uy * uz);
        R[8] = 1.0f + oc * (-(ux * ux + uy * uy));

        float jx = jr[j * 3 + 0], jy = jr[j * 3 + 1], jz = jr[j * 3 + 2];

        if (j == 0) {
            for (int k = 0; k < 9; ++k) Gr[k] = R[k];
            Gt[0] = jx; Gt[1] = jy; Gt[2] = jz;
        } else {
            float pjx = jr[(j - 1) * 3 + 0];
            float pjy = jr[(j - 1) * 3 + 1];
            float pjz = jr[(j - 1) * 3 + 2];
            float ltx = jx - pjx, lty = jy - pjy, ltz = jz - pjz;
            float nR[9], nT[3];
            for (int r = 0; r < 3; ++r) {
                float g0 = Gr[r * 3 + 0], g1 = Gr[r * 3 + 1], g2 = Gr[r * 3 + 2];
                nR[r * 3 + 0] = g0 * R[0] + g1 * R[3] + g2 * R[6];
                nR[r * 3 + 1] = g0 * R[1] + g1 * R[4] + g2 * R[7];
                nR[r * 3 + 2] = g0 * R[2] + g1 * R[5] + g2 * R[8];
                nT[r] = g0 * ltx + g1 * lty + g2 * ltz + Gt[r];
            }
            for (int k = 0; k < 9; ++k) Gr[k] = nR[k];
            Gt[0] = nT[0]; Gt[1] = nT[1]; Gt[2] = nT[2];
        }

        float tgx = Gt[0] - (Gr[0] * jx + Gr[1] * jy + Gr[2] * jz);
        float tgy = Gt[1] - (Gr[3] * jx + Gr[4] * jy + Gr[5] * jz);
        float tgz = Gt[2] - (Gr[6] * jx + Gr[7] * jy + Gr[8] * jz);
        float* Ao = A + ((size_t)b * kJ + j) * 12;
        Ao[0] = Gr[0]; Ao[1] = Gr[1]; Ao[2]  = Gr[2]; Ao[3]  = tgx;
        Ao[4] = Gr[3]; Ao[5] = Gr[4]; Ao[6]  = Gr[5]; Ao[7]  = tgy;
        Ao[8] = Gr[6]; Ao[9] = Gr[7]; Ao[10] = Gr[8]; Ao[11] = tgz;
    }
}

// ---------------------------------------------------------------------------
// Kernel 2: LBS skinning. b = blockIdx.x (XCD = b%8).
// ---------------------------------------------------------------------------
__global__ void skin_kernel(const float* __restrict__ A,
                            const float* __restrict__ sw,
                            const float* __restrict__ vt,
                            const float* __restrict__ scale,
                            const float* __restrict__ trans,
                            float4* __restrict__ Vw) {
    int b = blockIdx.x;
    int v = blockIdx.y * blockDim.x + threadIdx.x;
    __shared__ float sA[kJ * 12];
    if (threadIdx.x < kJ * 12) sA[threadIdx.x] = A[(size_t)b * kJ * 12 + threadIdx.x];
    __syncthreads();
    if (v >= kV) return;

    const float4* sw4 = (const float4*)(sw + (size_t)v * kJ);
    float w[kJ];
#pragma unroll
    for (int q = 0; q < 5; ++q) {
        float4 f = sw4[q];
        w[q * 4 + 0] = f.x; w[q * 4 + 1] = f.y;
        w[q * 4 + 2] = f.z; w[q * 4 + 3] = f.w;
    }

    float T[12];
#pragma unroll
    for (int k = 0; k < 12; ++k) T[k] = 0.0f;
#pragma unroll
    for (int j = 0; j < kJ; ++j) {
        float wj = w[j];
#pragma unroll
        for (int k = 0; k < 12; ++k) T[k] += wj * sA[j * 12 + k];
    }
    float x = vt[v * 3 + 0], y = vt[v * 3 + 1], z = vt[v * 3 + 2];
    float px = T[0] * x + T[1] * y + T[2]  * z + T[3];
    float py = T[4] * x + T[5] * y + T[6]  * z + T[7];
    float pz = T[8] * x + T[9] * y + T[10] * z + T[11];
    float s = scale[b];
    float tx = trans[b * 3 + 0], ty = trans[b * 3 + 1], tz = trans[b * 3 + 2];
    Vw[(size_t)b * kV + v] = make_float4(px * s + tx, py * s + ty, pz * s + tz, 0.0f);
}

// ---------------------------------------------------------------------------
// Kernel 3: frame + quat; v is always the base corner (2 gathers/face).
// Writes ONE 16B packed record: {px,py | pz,0 | q0,q1 | q2,q3} as 8xf16.
// ---------------------------------------------------------------------------
__global__ void frame_kernel(const float4* __restrict__ Vw,
                             const int* __restrict__ cnt,
                             const unsigned int* __restrict__ tri,
                             uint4* __restrict__ rec) {
    int b = blockIdx.x;
    int v = blockIdx.y * blockDim.x + threadIdx.x;
    if (v >= kV) return;
    const float4* base = Vw + (size_t)b * kV;
    float4 me = base[v];

    int deg = min(cnt[v], kCap);
    float sx = 0.0f, sy = 0.0f, sz = 0.0f;
    for (int i = 0; i < deg; ++i) {
        unsigned int r = tri[(size_t)i * kV + v];
        int ia = (int)(r & 0x7fffu);
        int ib = (int)((r >> 15) & 0x7fffu);
        bool swap = (r >> 30) != 0u;
        int j1 = swap ? ib : ia;
        int j2 = swap ? ia : ib;
        float4 c1 = base[j1];
        float4 c2 = base[j2];
        float e1x = c1.x - me.x, e1y = c1.y - me.y, e1z = c1.z - me.z;
        float e2x = c2.x - me.x, e2y = c2.y - me.y, e2z = c2.z - me.z;
        sx += e1y * e2z - e1z * e2y;
        sy += e1z * e2x - e1x * e2z;
        sz += e1x * e2y - e1y * e2x;
    }

    float ninv = rsqrtf(sx * sx + sy * sy + sz * sz + 1e-12f);
    float nx = sx * ninv, ny = sy * ninv, nz = sz * ninv;

    bool small = fabsf(nx) < 0.9f;
    float refx = small ? 1.0f : 0.0f;
    float refz = small ? 0.0f : 1.0f;
    float d = refx * nx + refz * nz;
    float tx0 = refx - d * nx, ty0 = -d * ny, tz0 = refz - d * nz;
    float tinv = rsqrtf(tx0 * tx0 + ty0 * ty0 + tz0 * tz0 + 1e-12f);
    float tx = tx0 * tinv, ty = ty0 * tinv, tz = tz0 * tinv;

    float btx = ny * tz - nz * ty;
    float bty = nz * tx - nx * tz;
    float btz = nx * ty - ny * tx;

    float r00 = tx, r01 = btx, r02 = nx;
    float r10 = ty, r11 = bty, r12 = ny;
    float r20 = tz, r21 = btz, r22 = nz;
    float tr = r00 + r11 + r22;
    float q0, q1, q2, q3;
    if (tr > 0.0f) {
        float s = sqrtf(fmaxf(tr + 1.0f, kEps)) * 2.0f;
        q0 = 0.25f * s;
        q1 = (r21 - r12) / s;
        q2 = (r02 - r20) / s;
        q3 = (r10 - r01) / s;
    } else if (r00 > r11 && r00 > r22) {
        float s = sqrtf(fmaxf(1.0f + r00 - r11 - r22, kEps)) * 2.0f;
        q0 = (r21 - r12) / s;
        q1 = 0.25f * s;
        q2 = (r01 + r10) / s;
        q3 = (r02 + r20) / s;
    } else if (r11 > r22) {
        float s = sqrtf(fmaxf(1.0f + r11 - r00 - r22, kEps)) * 2.0f;
        q0 = (r02 - r20) / s;
        q1 = (r01 + r10) / s;
        q2 = 0.25f * s;
        q3 = (r12 + r21) / s;
    } else {
        float s = sqrtf(fmaxf(1.0f + r22 - r00 - r11, kEps)) * 2.0f;
        q0 = (r10 - r01) / s;
        q1 = (r02 + r20) / s;
        q2 = (r12 + r21) / s;
        q3 = 0.25f * s;
    }
    float qinv = rsqrtf(q0 * q0 + q1 * q1 + q2 * q2 + q3 * q3 + 1e-12f);
    q0 *= qinv; q1 *= qinv; q2 *= qinv; q3 *= qinv;

    uint4 r16;
    r16.x = pack2h(me.x, me.y);
    r16.y = pack2h(me.z, 0.0f);
    r16.z = pack2h(q0, q1);
    r16.w = pack2h(q2, q3);
    rec[(size_t)b * kV + v] = r16;
}

// ---------------------------------------------------------------------------
// FUSED finalize (NPT=4): one uint4 gather per gaussian; rot written with
// nt-stores (aligned full lines, no amplification), rest via L2.
// ---------------------------------------------------------------------------
__global__ void finalize_all_kernel(const uint4* __restrict__ rec,
                                    const int* __restrict__ vidx,
                                    const float* __restrict__ poff,
                                    const float* __restrict__ quat,
                                    const float* __restrict__ craw,
                                    const float* __restrict__ oraw,
                                    const float* __restrict__ lsc,
                                    float* __restrict__ out) {
    int b = blockIdx.x;
    int qi = blockIdx.y * blockDim.x + threadIdx.x;
    if (qi >= kN / 4) return;
    int n0 = qi * 4;

    int4 vi = *(const int4*)(vidx + n0);
    const uint4* rb = rec + (size_t)b * kV;

    uint4 r[4];
    r[0] = rb[vi.x];
    r[1] = rb[vi.y];
    r[2] = rb[vi.z];
    r[3] = rb[vi.w];

    const float4* po = (const float4*)(poff + (size_t)n0 * 3);
    float4 oa = po[0], ob = po[1], oc = po[2];
    float off[4][3] = {{oa.x, oa.y, oa.z}, {oa.w, ob.x, ob.y},
                       {ob.z, ob.w, oc.x}, {oc.y, oc.z, oc.w}};

    const float4* lq4 = (const float4*)(quat + (size_t)n0 * 4);

    float m[4][3];
    float4 rotv[4];
#pragma unroll
    for (int k = 0; k < 4; ++k) {
        float2 pxy = unpack2h(r[k].x);
        float2 pz_ = unpack2h(r[k].y);
        float2 q01 = unpack2h(r[k].z);
        float2 q23 = unpack2h(r[k].w);
        float w = q01.x, x = q01.y, y = q23.x, z = q23.y;

        float tx = 1.0f - 2.0f * (y * y + z * z);
        float ty = 2.0f * (x * y + w * z);
        float tz = 2.0f * (x * z - w * y);
        float btx = 2.0f * (x * y - w * z);
        float bty = 1.0f - 2.0f * (x * x + z * z);
        float btz = 2.0f * (y * z + w * x);
        float nx = 2.0f * (x * z + w * y);
        float ny = 2.0f * (y * z - w * x);
        float nz = 1.0f - 2.0f * (x * x + y * y);

        float o0 = off[k][0], o1 = off[k][1], o2 = off[k][2];
        m[k][0] = pxy.x + o0 * tx + o1 * btx + o2 * nx;
        m[k][1] = pxy.y + o0 * ty + o1 * bty + o2 * ny;
        m[k][2] = pz_.x + o0 * tz + o1 * btz + o2 * nz;

        float4 lq = lq4[k];
        float lw = lq.x, lx = lq.y, ly = lq.z, lz = lq.w;
        float linv = rsqrtf(lw * lw + lx * lx + ly * ly + lz * lz + 1e-12f);
        lw *= linv; lx *= linv; ly *= linv; lz *= linv;

        rotv[k] = make_float4(w * lw - x * lx - y * ly - z * lz,
                              w * lx + x * lw + y * lz - z * ly,
                              w * ly - x * lz + y * lw + z * lx,
                              w * lz + x * ly - y * lx + z * lw);
    }

    const float4* cr4 = (const float4*)(craw + (size_t)n0 * 3);
    float4 ca = cr4[0], cb = cr4[1], cc = cr4[2];
    float4 ov = *(const float4*)(oraw + n0);
    const float4* ls4 = (const float4*)(lsc + (size_t)n0 * 3);
    float4 la = ls4[0], lb = ls4[1], lc = ls4[2];

    float4 sa = make_float4(sigm(ca.x), sigm(ca.y), sigm(ca.z), sigm(ca.w));
    float4 sb = make_float4(sigm(cb.x), sigm(cb.y), sigm(cb.z), sigm(cb.w));
    float4 sc = make_float4(sigm(cc.x), sigm(cc.y), sigm(cc.z), sigm(cc.w));
    float4 so = make_float4(sigm(ov.x), sigm(ov.y), sigm(ov.z), sigm(ov.w));
    float4 ea = make_float4(eclip(la.x), eclip(la.y), eclip(la.z), eclip(la.w));
    float4 eb = make_float4(eclip(lb.x), eclip(lb.y), eclip(lb.z), eclip(lb.w));
    float4 ec = make_float4(eclip(lc.x), eclip(lc.y), eclip(lc.z), eclip(lc.w));

    size_t bn0 = (size_t)b * kN + n0;
    float4* mo = (float4*)(out + OFF_MEANS + bn0 * 3);
    mo[0] = make_float4(m[0][0], m[0][1], m[0][2], m[1][0]);
    mo[1] = make_float4(m[1][1], m[1][2], m[2][0], m[2][1]);
    mo[2] = make_float4(m[2][2], m[3][0], m[3][1], m[3][2]);
    float* ro = out + OFF_ROT + bn0 * 4;
    nt_store4v(ro + 0,  rotv[0]);
    nt_store4v(ro + 4,  rotv[1]);
    nt_store4v(ro + 8,  rotv[2]);
    nt_store4v(ro + 12, rotv[3]);
    float4* co = (float4*)(out + OFF_COLORS + bn0 * 3);
    co[0] = sa; co[1] = sb; co[2] = sc;
    *(float4*)(out + OFF_OPAC + bn0) = so;
    float4* sco = (float4*)(out + OFF_SCALE + bn0 * 3);
    sco[0] = ea; sco[1] = eb; sco[2] = ec;
}

// ---------------------------------------------------------------------------
// Fallback kernels (ws too small): R10 structure with f32 rec in d_out.
// ---------------------------------------------------------------------------
__global__ void frame_f32_kernel(const float4* __restrict__ Vw,
                                 const int* __restrict__ cnt,
                                 const unsigned int* __restrict__ tri,
                                 float4* __restrict__ rec) {
    int b = blockIdx.x;
    int v = blockIdx.y * blockDim.x + threadIdx.x;
    if (v >= kV) return;
    const float4* base = Vw + (size_t)b * kV;
    float4 me = base[v];

    int deg = min(cnt[v], kCap);
    float sx = 0.0f, sy = 0.0f, sz = 0.0f;
    for (int i = 0; i < deg; ++i) {
        unsigned int r = tri[(size_t)i * kV + v];
        int ia = (int)(r & 0x7fffu);
        int ib = (int)((r >> 15) & 0x7fffu);
        bool swap = (r >> 30) != 0u;
        int j1 = swap ? ib : ia;
        int j2 = swap ? ia : ib;
        float4 c1 = base[j1];
        float4 c2 = base[j2];
        float e1x = c1.x - me.x, e1y = c1.y - me.y, e1z = c1.z - me.z;
        float e2x = c2.x - me.x, e2y = c2.y - me.y, e2z = c2.z - me.z;
        sx += e1y * e2z - e1z * e2y;
        sy += e1z * e2x - e1x * e2z;
        sz += e1x * e2y - e1y * e2x;
    }

    float ninv = rsqrtf(sx * sx + sy * sy + sz * sz + 1e-12f);
    float nx = sx * ninv, ny = sy * ninv, nz = sz * ninv;

    bool small = fabsf(nx) < 0.9f;
    float refx = small ? 1.0f : 0.0f;
    float refz = small ? 0.0f : 1.0f;
    float d = refx * nx + refz * nz;
    float tx0 = refx - d * nx, ty0 = -d * ny, tz0 = refz - d * nz;
    float tinv = rsqrtf(tx0 * tx0 + ty0 * ty0 + tz0 * tz0 + 1e-12f);
    float tx = tx0 * tinv, ty = ty0 * tinv, tz = tz0 * tinv;

    float btx = ny * tz - nz * ty;
    float bty = nz * tx - nx * tz;
    float btz = nx * ty - ny * tx;

    float r00 = tx, r01 = btx, r02 = nx;
    float r10 = ty, r11 = bty, r12 = ny;
    float r20 = tz, r21 = btz, r22 = nz;
    float tr = r00 + r11 + r22;
    float q0, q1, q2, q3;
    if (tr > 0.0f) {
        float s = sqrtf(fmaxf(tr + 1.0f, kEps)) * 2.0f;
        q0 = 0.25f * s;
        q1 = (r21 - r12) / s;
        q2 = (r02 - r20) / s;
        q3 = (r10 - r01) / s;
    } else if (r00 > r11 && r00 > r22) {
        float s = sqrtf(fmaxf(1.0f + r00 - r11 - r22, kEps)) * 2.0f;
        q0 = (r21 - r12) / s;
        q1 = 0.25f * s;
        q2 = (r01 + r10) / s;
        q3 = (r02 + r20) / s;
    } else if (r11 > r22) {
        float s = sqrtf(fmaxf(1.0f + r11 - r00 - r22, kEps)) * 2.0f;
        q0 = (r02 - r20) / s;
        q1 = (r01 + r10) / s;
        q2 = 0.25f * s;
        q3 = (r12 + r21) / s;
    } else {
        float s = sqrtf(fmaxf(1.0f + r22 - r00 - r11, kEps)) * 2.0f;
        q0 = (r10 - r01) / s;
        q1 = (r02 + r20) / s;
        q2 = (r12 + r21) / s;
        q3 = 0.25f * s;
    }
    float qinv = rsqrtf(q0 * q0 + q1 * q1 + q2 * q2 + q3 * q3 + 1e-12f);
    q0 *= qinv; q1 *= qinv; q2 *= qinv; q3 *= qinv;

    size_t ro = ((size_t)b * kV + v) * 2;
    rec[ro + 0] = make_float4(me.x, me.y, me.z, 0.0f);
    rec[ro + 1] = make_float4(q0, q1, q2, q3);
}

__global__ void finalize_mr4_kernel(const float4* __restrict__ rec,
                                    const int* __restrict__ vidx,
                                    const float* __restrict__ poff,
                                    const float* __restrict__ quat,
                                    float* __restrict__ out) {
    int b = blockIdx.x;
    int qi = blockIdx.y * blockDim.x + threadIdx.x;
    if (qi >= kN / 4) return;
    int n0 = qi * 4;

    int4 vi = *(const int4*)(vidx + n0);
    const float4* rb = rec + (size_t)b * kV * 2;

    float4 p[4], fq[4];
    p[0] = rb[(size_t)vi.x * 2]; fq[0] = rb[(size_t)vi.x * 2 + 1];
    p[1] = rb[(size_t)vi.y * 2]; fq[1] = rb[(size_t)vi.y * 2 + 1];
    p[2] = rb[(size_t)vi.z * 2]; fq[2] = rb[(size_t)vi.z * 2 + 1];
    p[3] = rb[(size_t)vi.w * 2]; fq[3] = rb[(size_t)vi.w * 2 + 1];

    const float4* po = (const float4*)(poff + (size_t)n0 * 3);
    float4 oa = po[0], ob = po[1], oc = po[2];
    float off[4][3] = {{oa.x, oa.y, oa.z}, {oa.w, ob.x, ob.y},
                       {ob.z, ob.w, oc.x}, {oc.y, oc.z, oc.w}};

    const float4* lq4 = (const float4*)(quat + (size_t)n0 * 4);

    float m[4][3];
    float4 rotv[4];
#pragma unroll
    for (int k = 0; k < 4; ++k) {
        float w = fq[k].x, x = fq[k].y, y = fq[k].z, z = fq[k].w;
        float tx = 1.0f - 2.0f * (y * y + z * z);
        float ty = 2.0f * (x * y + w * z);
        float tz = 2.0f * (x * z - w * y);
        float btx = 2.0f * (x * y - w * z);
        float bty = 1.0f - 2.0f * (x * x + z * z);
        float btz = 2.0f * (y * z + w * x);
        float nx = 2.0f * (x * z + w * y);
        float ny = 2.0f * (y * z - w * x);
        float nz = 1.0f - 2.0f * (x * x + y * y);

        float o0 = off[k][0], o1 = off[k][1], o2 = off[k][2];
        m[k][0] = p[k].x + o0 * tx + o1 * btx + o2 * nx;
        m[k][1] = p[k].y + o0 * ty + o1 * bty + o2 * ny;
        m[k][2] = p[k].z + o0 * tz + o1 * btz + o2 * nz;

        float4 lq = lq4[k];
        float lw = lq.x, lx = lq.y, ly = lq.z, lz = lq.w;
        float linv = rsqrtf(lw * lw + lx * lx + ly * ly + lz * lz + 1e-12f);
        lw *= linv; lx *= linv; ly *= linv; lz *= linv;

        rotv[k] = make_float4(w * lw - x * lx - y * ly - z * lz,
                              w * lx + x * lw + y * lz - z * ly,
                              w * ly - x * lz + y * lw + z * lx,
                              w * lz + x * ly - y * lx + z * lw);
    }

    size_t bn0 = (size_t)b * kN + n0;
    float4* mo = (float4*)(out + OFF_MEANS + bn0 * 3);
    mo[0] = make_float4(m[0][0], m[0][1], m[0][2], m[1][0]);
    mo[1] = make_float4(m[1][1], m[1][2], m[2][0], m[2][1]);
    mo[2] = make_float4(m[2][2], m[3][0], m[3][1], m[3][2]);
    float4* ro = (float4*)(out + OFF_ROT + bn0 * 4);
    ro[0] = rotv[0]; ro[1] = rotv[1]; ro[2] = rotv[2]; ro[3] = rotv[3];
}

__global__ void finalize_cos_kernel(const float* __restrict__ craw,
                                    const float* __restrict__ oraw,
                                    const float* __restrict__ lsc,
                                    float* __restrict__ out) {
    int b = blockIdx.x;
    int q = blockIdx.y * blockDim.x + threadIdx.x;
    if (q >= kN / 4) return;
    int n0 = q * 4;

    const float4* cr4 = (const float4*)(craw + (size_t)n0 * 3);
    float4 ca = cr4[0], cb = cr4[1], cc = cr4[2];
    float4 ov = *(const float4*)(oraw + n0);
    const float4* ls4 = (const float4*)(lsc + (size_t)n0 * 3);
    float4 la = ls4[0], lb = ls4[1], lc = ls4[2];

    float4 sa = make_float4(sigm(ca.x), sigm(ca.y), sigm(ca.z), sigm(ca.w));
    float4 sb = make_float4(sigm(cb.x), sigm(cb.y), sigm(cb.z), sigm(cb.w));
    float4 sc = make_float4(sigm(cc.x), sigm(cc.y), sigm(cc.z), sigm(cc.w));
    float4 so = make_float4(sigm(ov.x), sigm(ov.y), sigm(ov.z), sigm(ov.w));
    float4 ea = make_float4(eclip(la.x), eclip(la.y), eclip(la.z), eclip(la.w));
    float4 eb = make_float4(eclip(lb.x), eclip(lb.y), eclip(lb.z), eclip(lb.w));
    float4 ec = make_float4(eclip(lc.x), eclip(lc.y), eclip(lc.z), eclip(lc.w));

    size_t bn0 = (size_t)b * kN + n0;
    float4* co = (float4*)(out + OFF_COLORS + bn0 * 3);
    co[0] = sa; co[1] = sb; co[2] = sc;
    *(float4*)(out + OFF_OPAC + bn0) = so;
    float4* sco = (float4*)(out + OFF_SCALE + bn0 * 3);
    sco[0] = ea; sco[1] = eb; sco[2] = ec;
}

extern "C" void kernel_launch(void* const* d_in, const int* in_sizes, int n_in,
                              void* d_out, int out_size, void* d_ws, size_t ws_size,
                              hipStream_t stream) {
    const float* pose  = (const float*)d_in[0];
    const float* trans = (const float*)d_in[1];
    const float* scale = (const float*)d_in[2];
    const float* vt    = (const float*)d_in[3];
    const float* sw    = (const float*)d_in[4];
    const float* jr    = (const float*)d_in[5];
    const float* poff  = (const float*)d_in[6];
    const float* craw  = (const float*)d_in[7];
    const float* oraw  = (const float*)d_in[8];
    const float* lsc   = (const float*)d_in[9];
    const float* quat  = (const float*)d_in[10];
    const int*   vidx  = (const int*)d_in[11];
    const int*   faces = (const int*)d_in[12];
    float* out = (float*)d_out;
    char* ws = (char*)d_ws;

    float*        A   = (float*)(ws + WS_A);
    int*          cnt = (int*)(ws + WS_CNT);
    unsigned int* tri = (unsigned int*)(ws + WS_TRI);

    dim3 gV(kB, (kV + 255) / 256);
    dim3 gQ(kB, (kN / 4 + 255) / 256);

    zero_cnt_kernel<<<(kV + 255) / 256, 256, 0, stream>>>(cnt);
    fill_bucket_kernel<<<(kF + 255) / 256, 256, 0, stream>>>(faces, cnt, tri);
    jt_kernel<<<1, 64, 0, stream>>>(pose, jr, A);

    if (ws_size >= WS_END) {
        uint4*  rec = (uint4*)(ws + WS_REC);
        float4* Vw  = (float4*)(ws + WS_VW);

        skin_kernel<<<gV, 256, 0, stream>>>(A, sw, vt, scale, trans, Vw);
        frame_kernel<<<gV, 256, 0, stream>>>(Vw, cnt, tri, rec);
        finalize_all_kernel<<<gQ, 256, 0, stream>>>(rec, vidx, poff, quat,
                                                    craw, oraw, lsc, out);
    } else {
        float4* rec = (float4*)(out + OFF_OPAC);
        float4* Vw  = (float4*)(out + OFF_SCALE);

        skin_kernel<<<gV, 256, 0, stream>>>(A, sw, vt, scale, trans, Vw);
        frame_f32_kernel<<<gV, 256, 0, stream>>>(Vw, cnt, tri, rec);
        finalize_mr4_kernel<<<gQ, 256, 0, stream>>>(rec, vidx, poff, quat, out);
        finalize_cos_kernel<<<gQ, 256, 0, stream>>>(craw, oraw, lsc, out);
    }
}